// Round 17
// baseline (30.595 us; speedup 1.0000x reference)
//
#include <hip/hip_runtime.h>

// MPS batched contraction via SITE PAIRING (R9/R11/R13-verified):
// G_P[l][pq][d] = Σ_m A_{2P}[l,p,m] A_{2P+1}[m,q,d],  xx[pq] = x_p * y_q,
// left'' = G_P(xx) left.  32 pairs, K=128 each, 32x32x16 f16 MFMA:
//   A-op (G): row d = lane&31, k = 8*(lane>>5) + e
//   B-op (U): col b = lane&31, same k;  C/D: col = lane&31,
//   row l = (reg&3) + 8*(reg>>2) + 4*(lane>>5)
// G-frag kf = pq*2+lh encodes l = 16*lh + (e&3) + 8*(e>>2) + 4*h =>
//   U_frag(kf) = f16(left[e + 8*lh]) * xx[pq]  -- SAME LANE.
//
// R17 = R13 base + COUNTED-VMCNT PIPELINE (guide T3/T4): R1-R16 falsified
// LDS BW, chain depth, G pipe, x path, prep, TLP; the never-varied constant
// was __syncthreads() per chunk = compiler-inserted vmcnt(0) full drain
// (measured ~6600cy/chunk vs ~1500cy work = 77% overhead, matching the
// guide's m233 2-phase pathology; m218's counted-vmcnt fix = +38-73%).
// Now: 1-pair chunks (8KB) TRIPLE-buffered, stage issued 2 chunks ahead,
// loop barrier = raw `s_waitcnt vmcnt(2); s_barrier` (loads stay in flight
// across barriers; vmcnt(0) only at the tail). Safety: each wave's ds_read
// data is register-resident (lgkm-forced by MFMA uses) before its barrier,
// and stage(C+2) writes buf[(C+2)%3] which no wave can still be reading.
// Bonus: xx products precomputed in the x prologue (4 muls/pair/wave out
// of the loop, single-rounded).

typedef _Float16 half8 __attribute__((ext_vector_type(8)));
typedef _Float16 half4 __attribute__((ext_vector_type(4)));
typedef float floatx16 __attribute__((ext_vector_type(16)));
typedef float f32x4 __attribute__((ext_vector_type(4)));

#define NPAIRS 32
#define GCH1 4096       // halfs per 1-pair chunk = 8 KB
#define XSTRIDE 129     // padded half4 units per pair line (bank spread)

// ---------------- prep: one block per (pair, pq) (R16-proven) -------------
__global__ void mps_prep_pair(const float* __restrict__ A, _Float16* __restrict__ Gf) {
    __shared__ float sA[1024];   // [l][m]
    __shared__ float sB[1024];   // [m][d]
    __shared__ float sG[1024];   // [l][d]
    const int blk = blockIdx.x;          // 0..127 = P*4 + pq
    const int P   = blk >> 2;
    const int pq  = blk & 3;
    const int p   = pq >> 1, q = pq & 1;
    const int tid = threadIdx.x;         // 0..255
    const int row = tid >> 3;            // 0..31
    const int c4  = (tid & 7) * 4;       // 0,4,...,28

    *(f32x4*)&sA[row * 32 + c4] =
        *(const f32x4*)(A + ((size_t)(2 * P) * 32 + row) * 64 + p * 32 + c4);
    *(f32x4*)&sB[row * 32 + c4] =
        *(const f32x4*)(A + ((size_t)(2 * P + 1) * 32 + row) * 64 + q * 32 + c4);
    __syncthreads();
    {
        f32x4 acc;
        acc[0] = 0.f; acc[1] = 0.f; acc[2] = 0.f; acc[3] = 0.f;
        for (int m = 0; m < 32; ++m) {
            const float av = sA[row * 32 + m];
            const f32x4 bv = *(const f32x4*)&sB[m * 32 + c4];
            acc[0] += av * bv[0]; acc[1] += av * bv[1];
            acc[2] += av * bv[2]; acc[3] += av * bv[3];
        }
        *(f32x4*)&sG[row * 32 + c4] = acc;
    }
    __syncthreads();
    if (tid < 128) {
        const int lh   = tid >> 6;
        const int lane = tid & 63;
        const int h    = lane >> 5;
        const int d    = lane & 31;
        half8 v;
#pragma unroll
        for (int e = 0; e < 8; ++e) {
            const int l = 16 * lh + (e & 3) + 8 * (e >> 2) + 4 * h;
            v[e] = (_Float16)sG[l * 32 + d];
        }
        reinterpret_cast<half8*>(Gf)[((size_t)P * 8 + pq * 2 + lh) * 64 + lane] = v;
    }
}

// ---------------- main kernel ----------------
#define MF32(A_, B_, C_) __builtin_amdgcn_mfma_f32_32x32x16_f16(A_, B_, C_, 0, 0, 0)

// Counted-vmcnt barriers (no full drain in steady state).
#define PB2() asm volatile("s_waitcnt vmcnt(2)\n\ts_barrier" ::: "memory")
#define PB0() asm volatile("s_waitcnt vmcnt(0)\n\ts_barrier" ::: "memory")

// Stage 1-pair chunk C into buffer BUF: 8 recs of 1KB, 4 waves x 2 recs.
#define STAGE1(C, BUF)                                                        \
    {                                                                         \
        _Pragma("unroll")                                                     \
        for (int r_ = 0; r_ < 2; ++r_) {                                      \
            const int rec_ = r_ * 4 + wid;                                    \
            const _Float16* g_ = Gf + (size_t)(C) * GCH1 + rec_ * 512 + lane * 8; \
            __builtin_amdgcn_global_load_lds(                                 \
                (const __attribute__((address_space(1))) void*)g_,            \
                (__attribute__((address_space(3))) void*)&smG[(BUF) * GCH1 + rec_ * 512], \
                16, 0, 0);                                                    \
        }                                                                     \
    }

// One pair from LDS buffer BUF: xw quad (precomputed products), 8 JIT G
// ds_reads, FA cvt from acc, 8-MFMA in-place chain (R13-proven fastest form).
#define PAIRDO(BUF, P)                                                        \
    {                                                                         \
        const half4 xw_ = smX[(P) * XSTRIDE + r];                             \
        half8 G_[8];                                                          \
        _Pragma("unroll")                                                     \
        for (int f_ = 0; f_ < 8; ++f_)                                        \
            G_[f_] = *(const half8*)&smG[(BUF) * GCH1 + ((f_ * 64 + lane)) * 8]; \
        half8 FA0_, FA1_;                                                     \
        _Pragma("unroll")                                                     \
        for (int i_ = 0; i_ < 8; ++i_) {                                      \
            FA0_[i_] = (_Float16)acc[i_];                                     \
            FA1_[i_] = (_Float16)acc[8 + i_];                                 \
        }                                                                     \
        floatx16 t_;                                                          \
        t_ = MF32(G_[0], FA0_ * xw_[0], zv);                                  \
        t_ = MF32(G_[1], FA1_ * xw_[0], t_);                                  \
        t_ = MF32(G_[2], FA0_ * xw_[1], t_);                                  \
        t_ = MF32(G_[3], FA1_ * xw_[1], t_);                                  \
        t_ = MF32(G_[4], FA0_ * xw_[2], t_);                                  \
        t_ = MF32(G_[5], FA1_ * xw_[2], t_);                                  \
        t_ = MF32(G_[6], FA0_ * xw_[3], t_);                                  \
        t_ = MF32(G_[7], FA1_ * xw_[3], t_);                                  \
        acc = t_;                                                             \
    }

__global__ __launch_bounds__(256, 2) void mps_main(const float* __restrict__ x,
                                                   const _Float16* __restrict__ Gf,
                                                   float* __restrict__ out) {
    __shared__ __align__(16) _Float16 smG[3 * GCH1];      // 24 KB (3 bufs)
    __shared__ __align__(8)  half4    smX[32 * XSTRIDE];  // 33 KB, [pair][row]

    const int tid  = threadIdx.x;
    const int lane = tid & 63;
    const int wid  = tid >> 6;                 // 0..3
    const int brow = blockIdx.x * 128;         // block's first batch row
    const int col  = lane & 31;
    const int r    = wid * 32 + col;           // this wave's row within block

    STAGE1(0, 0);
    STAGE1(1, 1);

    // x -> LDS: PRODUCTS xx[pq] = x_p*y_q per (pair,row), f16, transposed
    // [pair][row]; coalesced f32x4 global reads (lane-consecutive quads).
#pragma unroll
    for (int i = 0; i < 16; ++i) {
        const int j   = i * 256 + tid;         // 0..4095
        const int row = j >> 5, q = j & 31;
        const f32x4 v = *(const f32x4*)(x + (size_t)(brow + row) * 128 + 4 * q);
        half4 hv;                               // (x0y0, x0y1, x1y0, x1y1)
        hv[0] = (_Float16)(v[0] * v[2]); hv[1] = (_Float16)(v[0] * v[3]);
        hv[2] = (_Float16)(v[1] * v[2]); hv[3] = (_Float16)(v[1] * v[3]);
        smX[q * XSTRIDE + row] = hv;
    }

    floatx16 zv;
#pragma unroll
    for (int i = 0; i < 16; ++i) zv[i] = 0.f;

    // acc = left[l], l = (reg&3) + 8*(reg>>2) + 4*(lane>>5)
    floatx16 acc;
#pragma unroll
    for (int i = 0; i < 16; ++i) acc[i] = 0.f;
    if (lane < 32) acc[0] = 1.f;               // left0 = e0

    __syncthreads();                            // prologue drain (once): x,
                                                // chunks 0,1 all resident

    // 32 pipelined chunks: stage C+2, compute C, counted-vmcnt barrier.
#pragma unroll
    for (int C = 0; C < 32; ++C) {
        if (C < 30) STAGE1(C + 2, (C + 2) % 3);
        PAIRDO(C % 3, C)
        if (C < 30)      PB2();                 // chunk C+1 ready; C+2 in flight
        else if (C == 30) PB0();                // tail: drain chunk 31
    }

    // out[b] = left_final[l=0]: reg 0, h=0 -> lanes 0..31
    if (lane < 32) out[brow + wid * 32 + lane] = acc[0];
}

extern "C" void kernel_launch(void* const* d_in, const int* in_sizes, int n_in,
                              void* d_out, int out_size, void* d_ws, size_t ws_size,
                              hipStream_t stream) {
    const float* x = (const float*)d_in[0];   // [65536][64][2] f32
    const float* A = (const float*)d_in[1];   // [64][32][2][32] f32
    float* outp = (float*)d_out;              // [65536] f32
    _Float16* Gf = (_Float16*)d_ws;           // 256 KB pair-fragment fp16

    hipLaunchKernelGGL(mps_prep_pair, dim3(NPAIRS * 4), dim3(256), 0, stream, A, Gf);
    hipLaunchKernelGGL(mps_main, dim3(65536 / 128), dim3(256), 0, stream, x, Gf, outp);
}